// Round 1
// baseline (88.648 us; speedup 1.0000x reference)
//
#include <hip/hip_runtime.h>

// ---------- types ----------
using f32x4  = __attribute__((ext_vector_type(4))) float;
using bf16x8 = __attribute__((ext_vector_type(8))) short;   // 8 bf16 in 4 VGPRs

__device__ __forceinline__ unsigned short f2bf(float f) {
    union { float f; unsigned int u; } v; v.f = f;
    unsigned int r = v.u + 0x7fffu + ((v.u >> 16) & 1u);  // RNE
    return (unsigned short)(r >> 16);
}

// ---------- transpose X[b][C][P] f32 -> Y[b][P][C] bf16 ----------
__global__ __launch_bounds__(256) void transpose_f32_to_bf16(
    const float* __restrict__ x, unsigned short* __restrict__ y, int C, int P) {
    __shared__ float tile[32][33];
    int b  = blockIdx.z;
    int p0 = blockIdx.x * 32;
    int c0 = blockIdx.y * 32;
    const float* xb = x + (size_t)b * C * P;
    unsigned short* yb = y + (size_t)b * C * P;
    int tx = threadIdx.x, ty = threadIdx.y;
    #pragma unroll
    for (int i = 0; i < 32; i += 8)
        tile[ty + i][tx] = xb[(size_t)(c0 + ty + i) * P + (p0 + tx)];
    __syncthreads();
    // packed 2x bf16 stores: 512 uint writes per block, 2 per thread
    int tid = ty * 32 + tx;
    #pragma unroll
    for (int k = 0; k < 2; ++k) {
        int wi = tid * 2 + k;          // 0..511
        int pl = wi >> 4;              // 0..31  local p row
        int cp = wi & 15;              // 0..15  c-pair
        unsigned short lo = f2bf(tile[2 * cp][pl]);
        unsigned short hi = f2bf(tile[2 * cp + 1][pl]);
        unsigned int packed = (unsigned int)lo | ((unsigned int)hi << 16);
        *reinterpret_cast<unsigned int*>(&yb[(size_t)(p0 + pl) * C + (c0 + 2 * cp)]) = packed;
    }
}

// ---------- conv as GEMM + fused gather ----------
// Block: one (b, image-row r, q-half h). Computes G[p=r*64..r*64+64)[q=128h..128h+128)
// G[p][q] = sum_c St[b][p][c] * Dt[b][q][c], then scatters 16-tap sums into mm.
__global__ __launch_bounds__(256) void conv_gemm(
    const unsigned short* __restrict__ St,   // [16][4096][256] bf16
    const unsigned short* __restrict__ Dt,   // [16][256][256]  bf16
    float* __restrict__ mm) {                // [16][49][49]    f32 (pre-zeroed)
    __shared__ float gt[64][130];            // 64 p-rows x 128 q (+2 pad) = 33.3 KB

    int blk  = blockIdx.x;        // b*128 + r*2 + h
    int b    = blk >> 7;
    int rest = blk & 127;
    int r    = rest >> 1;
    int h    = rest & 1;

    int tid  = threadIdx.x;
    int wave = tid >> 6;          // 0..3
    int lane = tid & 63;
    int m    = lane & 15;
    int kg   = lane >> 4;         // 0..3, k-group (8 bf16 each)

    const unsigned short* A = St + ((size_t)b * 4096 + (size_t)r * 64) * 256;
    const unsigned short* B = Dt + ((size_t)b * 256 + 128 * h + 32 * wave) * 256;

    f32x4 acc[4][2];
    #pragma unroll
    for (int i = 0; i < 4; ++i)
        #pragma unroll
        for (int j = 0; j < 2; ++j)
            acc[i][j] = f32x4{0.f, 0.f, 0.f, 0.f};

    for (int c0 = 0; c0 < 256; c0 += 32) {
        bf16x8 af[4], bfq[2];
        #pragma unroll
        for (int pa = 0; pa < 4; ++pa)
            af[pa] = *reinterpret_cast<const bf16x8*>(A + (size_t)(16 * pa + m) * 256 + c0 + kg * 8);
        #pragma unroll
        for (int qb = 0; qb < 2; ++qb)
            bfq[qb] = *reinterpret_cast<const bf16x8*>(B + (size_t)(16 * qb + m) * 256 + c0 + kg * 8);
        #pragma unroll
        for (int pa = 0; pa < 4; ++pa)
            #pragma unroll
            for (int qb = 0; qb < 2; ++qb)
                acc[pa][qb] = __builtin_amdgcn_mfma_f32_16x16x32_bf16(af[pa], bfq[qb], acc[pa][qb], 0, 0, 0);
    }

    // C/D layout: col = lane&15, row = 4*(lane>>4) + t   [guide m89/m91]
    #pragma unroll
    for (int pa = 0; pa < 4; ++pa)
        #pragma unroll
        for (int qb = 0; qb < 2; ++qb)
            #pragma unroll
            for (int t = 0; t < 4; ++t)
                gt[16 * pa + 4 * kg + t][32 * wave + 16 * qb + m] = acc[pa][qb][t];

    __syncthreads();

    // gather: mm[b][y][x] += sum_j gt[x+j][(i-8h)*16+j],  i = r - y in [8h, 8h+8)
    int ilo = 8 * h;           if (r - 48 > ilo) ilo = r - 48;
    int ihi = 8 * h + 7;       if (r < ihi)      ihi = r;
    if (ilo <= ihi) {
        int ny = ihi - ilo + 1;
        int total = ny * 49;
        for (int o = tid; o < total; o += 256) {
            int i = ilo + o / 49;
            int x = o % 49;
            int y = r - i;
            int qrow = (i - 8 * h) * 16;
            float s = 0.f;
            #pragma unroll
            for (int j = 0; j < 16; ++j)
                s += gt[x + j][qrow + j];
            atomicAdd(&mm[(size_t)b * 2401 + y * 49 + x], s);
        }
    }
}

// ---------- fallback naive conv (tiny ws) ----------
__global__ __launch_bounds__(256) void conv_naive(
    const float* __restrict__ S, const float* __restrict__ D, float* __restrict__ mm) {
    int blk = blockIdx.x;            // b*2401 + y*49 + x
    int b = blk / 2401;
    int yx = blk % 2401;
    int y = yx / 49, x = yx % 49;
    int c = threadIdx.x;
    const float* Sp = S + (((size_t)b * 256 + c) * 64 + y) * 64 + x;
    const float* Dp = D + ((size_t)b * 256 + c) * 256;
    float s = 0.f;
    #pragma unroll
    for (int i = 0; i < 16; ++i)
        #pragma unroll 4
        for (int j = 0; j < 16; ++j)
            s += Sp[i * 64 + j] * Dp[i * 16 + j];
    __shared__ float red[256];
    red[c] = s;
    __syncthreads();
    for (int st = 128; st > 0; st >>= 1) {
        if (c < st) red[c] += red[c + st];
        __syncthreads();
    }
    if (c == 0) mm[blk] = red[0];
}

// ---------- global mean / rstd over 38416 values ----------
__global__ __launch_bounds__(1024) void stats_kernel(
    const float* __restrict__ mm, float* __restrict__ stats) {
    __shared__ float ssum[1024];
    __shared__ float ssq[1024];
    int tid = threadIdx.x;
    float s = 0.f, q = 0.f;
    for (int i = tid; i < 38416; i += 1024) {
        float v = mm[i];
        s += v; q += v * v;
    }
    ssum[tid] = s; ssq[tid] = q;
    __syncthreads();
    for (int st = 512; st > 0; st >>= 1) {
        if (tid < st) { ssum[tid] += ssum[tid + st]; ssq[tid] += ssq[tid + st]; }
        __syncthreads();
    }
    if (tid == 0) {
        float mean = ssum[0] / 38416.f;
        float var  = ssq[0] / 38416.f - mean * mean;
        stats[0] = mean;
        stats[1] = rsqrtf(var + 1e-5f);
    }
}

// ---------- normalize + bilinear 49x49 -> 256x256 ----------
__global__ __launch_bounds__(256) void bilinear_kernel(
    const float* __restrict__ mm, const float* __restrict__ stats,
    const float* __restrict__ gamma, const float* __restrict__ beta,
    float* __restrict__ out) {
    int idx = blockIdx.x * 256 + threadIdx.x;   // 16*256*256 = 1,048,576
    int b  = idx >> 16;
    int oy = (idx >> 8) & 255;
    int ox = idx & 255;
    const float scale = 49.0f / 256.0f;
    float cy = fminf(fmaxf((oy + 0.5f) * scale - 0.5f, 0.0f), 48.0f);
    int y0 = (int)cy; int y1 = min(y0 + 1, 48); float wy = cy - (float)y0;
    float cx = fminf(fmaxf((ox + 0.5f) * scale - 0.5f, 0.0f), 48.0f);
    int x0 = (int)cx; int x1 = min(x0 + 1, 48); float wx = cx - (float)x0;
    const float* mb = mm + (size_t)b * 2401;
    float v00 = mb[y0 * 49 + x0];
    float v01 = mb[y0 * 49 + x1];
    float v10 = mb[y1 * 49 + x0];
    float v11 = mb[y1 * 49 + x1];
    float r0 = v00 * (1.f - wy) + v10 * wy;
    float r1 = v01 * (1.f - wy) + v11 * wy;
    float v  = r0 * (1.f - wx) + r1 * wx;
    float mean = stats[0], rstd = stats[1];
    v = (v - mean) * rstd * gamma[0] + beta[0];
    out[idx] = v;
}

extern "C" void kernel_launch(void* const* d_in, const int* in_sizes, int n_in,
                              void* d_out, int out_size, void* d_ws, size_t ws_size,
                              hipStream_t stream) {
    const float* S     = (const float*)d_in[0];   // (16,256,64,64)
    const float* D     = (const float*)d_in[1];   // (16,256,16,16)
    const float* gamma = (const float*)d_in[2];   // (1,)
    const float* beta  = (const float*)d_in[3];   // (1,)
    float* out = (float*)d_out;                   // (16,1,256,256)

    char* ws = (char*)d_ws;
    const size_t sizeSt = (size_t)16 * 4096 * 256 * 2;  // 33,554,432
    const size_t sizeDt = (size_t)16 * 256 * 256 * 2;   //  2,097,152
    const size_t sizeMm = (size_t)38416 * 4;            //    153,664
    const size_t offSt = 0;
    const size_t offDt = offSt + sizeSt;
    const size_t offMm = offDt + sizeDt;
    const size_t offStats = offMm + sizeMm;
    const size_t needFast = offStats + 2 * sizeof(float);

    bool fast = (ws_size >= needFast);
    float* mm;
    float* stats;
    if (fast) {
        mm    = (float*)(ws + offMm);
        stats = (float*)(ws + offStats);
    } else {
        mm    = (float*)ws;
        stats = (float*)(ws + sizeMm);
    }

    if (fast) {
        unsigned short* St = (unsigned short*)(ws + offSt);
        unsigned short* Dt = (unsigned short*)(ws + offDt);
        hipMemsetAsync(mm, 0, sizeMm, stream);
        transpose_f32_to_bf16<<<dim3(128, 8, 16), dim3(32, 8), 0, stream>>>(S, St, 256, 4096);
        transpose_f32_to_bf16<<<dim3(8, 8, 16),  dim3(32, 8), 0, stream>>>(D, Dt, 256, 256);
        conv_gemm<<<2048, 256, 0, stream>>>(St, Dt, mm);
    } else {
        conv_naive<<<16 * 2401, 256, 0, stream>>>(S, D, mm);
    }
    stats_kernel<<<1, 1024, 0, stream>>>(mm, stats);
    bilinear_kernel<<<4096, 256, 0, stream>>>(mm, stats, gamma, beta, out);
}

// Round 2
// 53.197 us; speedup vs baseline: 1.6664x; 1.6664x over previous
//
#include <hip/hip_runtime.h>

// ---------- types ----------
using f32x4  = __attribute__((ext_vector_type(4))) float;
using bf16x8 = __attribute__((ext_vector_type(8))) short;   // 8 bf16 in 4 VGPRs

__device__ __forceinline__ unsigned short f2bf(float f) {
    union { float f; unsigned int u; } v; v.f = f;
    unsigned int r = v.u + 0x7fffu + ((v.u >> 16) & 1u);  // RNE
    return (unsigned short)(r >> 16);
}

__device__ __forceinline__ float bf2f(unsigned short u) {
    union { unsigned int u; float f; } v; v.u = ((unsigned int)u) << 16;
    return v.f;
}

// ---------- transpose D [16][256c][256q] f32 -> Dt [16][256q][256c] bf16, + zero mm ----------
__global__ __launch_bounds__(256) void transposeD_zero(
    const float* __restrict__ x, unsigned short* __restrict__ y, float* __restrict__ mm) {
    __shared__ float tile[32][33];
    int b  = blockIdx.z;
    int p0 = blockIdx.x * 32;      // q tile
    int c0 = blockIdx.y * 32;      // c tile
    const float* xb = x + (size_t)b * 256 * 256;
    unsigned short* yb = y + (size_t)b * 256 * 256;
    int tx = threadIdx.x, ty = threadIdx.y;
    #pragma unroll
    for (int i = 0; i < 32; i += 8)
        tile[ty + i][tx] = xb[(size_t)(c0 + ty + i) * 256 + (p0 + tx)];
    __syncthreads();
    int tid = ty * 32 + tx;
    #pragma unroll
    for (int k = 0; k < 2; ++k) {
        int wi = tid * 2 + k;          // 0..511
        int pl = wi >> 4;              // local q row
        int cp = wi & 15;              // c-pair
        unsigned short lo = f2bf(tile[2 * cp][pl]);
        unsigned short hi = f2bf(tile[2 * cp + 1][pl]);
        unsigned int packed = (unsigned int)lo | ((unsigned int)hi << 16);
        *reinterpret_cast<unsigned int*>(&yb[(size_t)(p0 + pl) * 256 + (c0 + 2 * cp)]) = packed;
    }
    // zero mm (38416 floats) using the 64 blocks with z==0
    if (blockIdx.z == 0) {
        int bid = blockIdx.y * 8 + blockIdx.x;       // 0..63
        for (int i = bid * 256 + tid; i < 38416; i += 64 * 256) mm[i] = 0.f;
    }
}

// ---------- fused conv: stage S->LDS(bf16,swizzled), GEMM vs Dt, gather into mm ----------
// Block = (b, image row r). Computes G[p=r*64 .. r*64+64)[q=0..256) and scatters
// 16-tap diagonal sums into mm via atomics.
__global__ __launch_bounds__(256) void conv_fused(
    const float* __restrict__ S,             // [16][256][64][64] f32
    const unsigned short* __restrict__ Dt,   // [16][256q][256c] bf16
    float* __restrict__ mm) {                // [16][49][49] f32 (pre-zeroed)
    // union: At swizzled bf16 [64 p][256 c] (32768 B)  /  gt bf16 [64][264] (33792 B)
    __shared__ __align__(16) char lds[64 * 264 * 2];
    char* base = lds;

    int b = blockIdx.x >> 6;
    int r = blockIdx.x & 63;
    int tid = threadIdx.x;

    // ---- stage A: S[b][c][r][0..63] -> At[p][c] bf16, XOR-swizzled ----
    // byte addr(p,c) = p*512 + (((c>>3) ^ (p&15)) << 4) + ((c&7)<<1)
    {
        int sub = tid & 3;
        int cl  = tid >> 2;                  // 0..63
        #pragma unroll
        for (int chunk = 0; chunk < 4; ++chunk) {
            int c = chunk * 64 + cl;
            const float* src = S + (((size_t)(b * 256 + c) * 64 + r) * 64);
            #pragma unroll
            for (int k = 0; k < 4; ++k) {
                int p = 16 * k + 4 * sub;
                f32x4 v = *reinterpret_cast<const f32x4*>(src + p);
                #pragma unroll
                for (int e = 0; e < 4; ++e) {
                    int pe = p + e;
                    int off = pe * 512 + ((((c >> 3) ^ (pe & 15))) << 4) + ((c & 7) << 1);
                    *reinterpret_cast<unsigned short*>(base + off) = f2bf(v[e]);
                }
            }
        }
    }
    __syncthreads();

    // ---- GEMM: wave w computes q in [64w, 64w+64), all 64 p rows, K=256 ----
    int w    = tid >> 6;
    int lane = tid & 63;
    int m    = lane & 15;
    int kg   = lane >> 4;

    const unsigned short* Db = Dt + ((size_t)(b * 256 + 64 * w)) * 256;

    f32x4 acc[4][4];
    #pragma unroll
    for (int i = 0; i < 4; ++i)
        #pragma unroll
        for (int j = 0; j < 4; ++j)
            acc[i][j] = f32x4{0.f, 0.f, 0.f, 0.f};

    #pragma unroll
    for (int step = 0; step < 8; ++step) {
        bf16x8 bfr[4];
        #pragma unroll
        for (int n = 0; n < 4; ++n)
            bfr[n] = *reinterpret_cast<const bf16x8*>(Db + (size_t)(16 * n + m) * 256 + step * 32 + kg * 8);
        bf16x8 af[4];
        #pragma unroll
        for (int pa = 0; pa < 4; ++pa) {
            int p = 16 * pa + m;
            int slot = (4 * step + kg) ^ m;          // p&15 == m
            af[pa] = *reinterpret_cast<const bf16x8*>(base + p * 512 + slot * 16);
        }
        #pragma unroll
        for (int pa = 0; pa < 4; ++pa)
            #pragma unroll
            for (int n = 0; n < 4; ++n)
                acc[pa][n] = __builtin_amdgcn_mfma_f32_16x16x32_bf16(af[pa], bfr[n], acc[pa][n], 0, 0, 0);
    }

    __syncthreads();   // all waves done reading At before overwrite

    // ---- dump G tile to LDS as bf16: gt[64 p][264] ----
    unsigned short* gt = (unsigned short*)base;
    #pragma unroll
    for (int pa = 0; pa < 4; ++pa)
        #pragma unroll
        for (int n = 0; n < 4; ++n)
            #pragma unroll
            for (int t = 0; t < 4; ++t) {
                int row = 16 * pa + 4 * kg + t;        // p local
                int col = 64 * w + 16 * n + m;         // q
                gt[row * 264 + col] = f2bf(acc[pa][n][t]);
            }
    __syncthreads();

    // ---- gather: mm[b][y=r-i][x] += sum_j G[x+j][16i+j] ----
    int ilo = (r > 48) ? (r - 48) : 0;
    int ihi = (r < 15) ? r : 15;
    int total = (ihi - ilo + 1) * 49;
    for (int o = tid; o < total; o += 256) {
        int i = ilo + o / 49;
        int x = o % 49;
        int y = r - i;
        float s = 0.f;
        int qb = 16 * i;
        #pragma unroll
        for (int j = 0; j < 16; ++j)
            s += bf2f(gt[(x + j) * 264 + qb + j]);
        atomicAdd(&mm[(size_t)b * 2401 + y * 49 + x], s);
    }
}

// ---------- fallback naive conv (tiny ws) ----------
__global__ __launch_bounds__(256) void conv_naive(
    const float* __restrict__ S, const float* __restrict__ D, float* __restrict__ mm) {
    int blk = blockIdx.x;            // b*2401 + y*49 + x
    int b = blk / 2401;
    int yx = blk % 2401;
    int y = yx / 49, x = yx % 49;
    int c = threadIdx.x;
    const float* Sp = S + (((size_t)b * 256 + c) * 64 + y) * 64 + x;
    const float* Dp = D + ((size_t)b * 256 + c) * 256;
    float s = 0.f;
    #pragma unroll
    for (int i = 0; i < 16; ++i)
        #pragma unroll 4
        for (int j = 0; j < 16; ++j)
            s += Sp[i * 64 + j] * Dp[i * 16 + j];
    __shared__ float red[256];
    red[c] = s;
    __syncthreads();
    for (int st = 128; st > 0; st >>= 1) {
        if (c < st) red[c] += red[c + st];
        __syncthreads();
    }
    if (c == 0) mm[blk] = red[0];
}

// ---------- global mean / rstd over 38416 values ----------
__global__ __launch_bounds__(1024) void stats_kernel(
    const float* __restrict__ mm, float* __restrict__ stats) {
    __shared__ float ssum[1024];
    __shared__ float ssq[1024];
    int tid = threadIdx.x;
    float s = 0.f, q = 0.f;
    for (int i = tid; i < 38416; i += 1024) {
        float v = mm[i];
        s += v; q += v * v;
    }
    ssum[tid] = s; ssq[tid] = q;
    __syncthreads();
    for (int st = 512; st > 0; st >>= 1) {
        if (tid < st) { ssum[tid] += ssum[tid + st]; ssq[tid] += ssq[tid + st]; }
        __syncthreads();
    }
    if (tid == 0) {
        float mean = ssum[0] / 38416.f;
        float var  = ssq[0] / 38416.f - mean * mean;
        stats[0] = mean;
        stats[1] = rsqrtf(var + 1e-5f);
    }
}

// ---------- normalize + bilinear 49x49 -> 256x256 ----------
__global__ __launch_bounds__(256) void bilinear_kernel(
    const float* __restrict__ mm, const float* __restrict__ stats,
    const float* __restrict__ gamma, const float* __restrict__ beta,
    float* __restrict__ out) {
    int idx = blockIdx.x * 256 + threadIdx.x;   // 16*256*256 = 1,048,576
    int b  = idx >> 16;
    int oy = (idx >> 8) & 255;
    int ox = idx & 255;
    const float scale = 49.0f / 256.0f;
    float cy = fminf(fmaxf((oy + 0.5f) * scale - 0.5f, 0.0f), 48.0f);
    int y0 = (int)cy; int y1 = min(y0 + 1, 48); float wy = cy - (float)y0;
    float cx = fminf(fmaxf((ox + 0.5f) * scale - 0.5f, 0.0f), 48.0f);
    int x0 = (int)cx; int x1 = min(x0 + 1, 48); float wx = cx - (float)x0;
    const float* mb = mm + (size_t)b * 2401;
    float v00 = mb[y0 * 49 + x0];
    float v01 = mb[y0 * 49 + x1];
    float v10 = mb[y1 * 49 + x0];
    float v11 = mb[y1 * 49 + x1];
    float r0 = v00 * (1.f - wy) + v10 * wy;
    float r1 = v01 * (1.f - wy) + v11 * wy;
    float v  = r0 * (1.f - wx) + r1 * wx;
    float mean = stats[0], rstd = stats[1];
    v = (v - mean) * rstd * gamma[0] + beta[0];
    out[idx] = v;
}

extern "C" void kernel_launch(void* const* d_in, const int* in_sizes, int n_in,
                              void* d_out, int out_size, void* d_ws, size_t ws_size,
                              hipStream_t stream) {
    const float* S     = (const float*)d_in[0];   // (16,256,64,64)
    const float* D     = (const float*)d_in[1];   // (16,256,16,16)
    const float* gamma = (const float*)d_in[2];   // (1,)
    const float* beta  = (const float*)d_in[3];   // (1,)
    float* out = (float*)d_out;                   // (16,1,256,256)

    char* ws = (char*)d_ws;
    const size_t sizeDt = (size_t)16 * 256 * 256 * 2;   // 2,097,152
    const size_t sizeMm = (size_t)38416 * 4;            //   153,664
    const size_t offDt = 0;
    const size_t offMm = offDt + sizeDt;
    const size_t offStats = offMm + sizeMm;
    const size_t needFast = offStats + 2 * sizeof(float);

    bool fast = (ws_size >= needFast);
    float* mm;
    float* stats;
    if (fast) {
        mm    = (float*)(ws + offMm);
        stats = (float*)(ws + offStats);
    } else {
        mm    = (float*)ws;
        stats = (float*)(ws + sizeMm);
    }

    if (fast) {
        unsigned short* Dt = (unsigned short*)(ws + offDt);
        transposeD_zero<<<dim3(8, 8, 16), dim3(32, 8), 0, stream>>>(D, Dt, mm);
        conv_fused<<<1024, 256, 0, stream>>>(S, Dt, mm);
    } else {
        conv_naive<<<16 * 2401, 256, 0, stream>>>(S, D, mm);
    }
    stats_kernel<<<1, 1024, 0, stream>>>(mm, stats);
    bilinear_kernel<<<4096, 256, 0, stream>>>(mm, stats, gamma, beta, out);
}

// Round 3
// 52.115 us; speedup vs baseline: 1.7010x; 1.0207x over previous
//
#include <hip/hip_runtime.h>

// ---------- types ----------
using f32x4  = __attribute__((ext_vector_type(4))) float;
using bf16x8 = __attribute__((ext_vector_type(8))) short;   // 8 bf16 in 4 VGPRs

__device__ __forceinline__ unsigned short f2bf(float f) {
    union { float f; unsigned int u; } v; v.f = f;
    unsigned int r = v.u + 0x7fffu + ((v.u >> 16) & 1u);  // RNE
    return (unsigned short)(r >> 16);
}

__device__ __forceinline__ float bf2f(unsigned short u) {
    union { unsigned int u; float f; } v; v.u = ((unsigned int)u) << 16;
    return v.f;
}

// ---------- transpose D [16][256c][256q] f32 -> Dt [16][256q][256c] bf16 ----------
__global__ __launch_bounds__(256) void transposeD(
    const float* __restrict__ x, unsigned short* __restrict__ y) {
    __shared__ float tile[32][33];
    int b  = blockIdx.z;
    int p0 = blockIdx.x * 32;      // q tile
    int c0 = blockIdx.y * 32;      // c tile
    const float* xb = x + (size_t)b * 256 * 256;
    unsigned short* yb = y + (size_t)b * 256 * 256;
    int tx = threadIdx.x, ty = threadIdx.y;
    #pragma unroll
    for (int i = 0; i < 32; i += 8)
        tile[ty + i][tx] = xb[(size_t)(c0 + ty + i) * 256 + (p0 + tx)];
    __syncthreads();
    int tid = ty * 32 + tx;
    #pragma unroll
    for (int k = 0; k < 2; ++k) {
        int wi = tid * 2 + k;          // 0..511
        int pl = wi >> 4;              // local q row
        int cp = wi & 15;              // c-pair
        unsigned short lo = f2bf(tile[2 * cp][pl]);
        unsigned short hi = f2bf(tile[2 * cp + 1][pl]);
        unsigned int packed = (unsigned int)lo | ((unsigned int)hi << 16);
        *reinterpret_cast<unsigned int*>(&yb[(size_t)(p0 + pl) * 256 + (c0 + 2 * cp)]) = packed;
    }
}

// ---------- fused conv: stage S->LDS(bf16,swizzled), GEMM vs Dt, partials to P ----------
// Block = (b, image row r). Computes G[p=r*64 .. r*64+64)[q=0..256) and writes
// 16-tap diagonal sums NON-ATOMICALLY to P[b][r][i][x].
__global__ __launch_bounds__(256, 4) void conv_fused(
    const float* __restrict__ S,             // [16][256][64][64] f32
    const unsigned short* __restrict__ Dt,   // [16][256q][256c] bf16
    float* __restrict__ P) {                 // [16][64][16][52] f32 partials
    // union: At swizzled bf16 [64 p][256 c] (32768 B)  /  gt bf16 [64][262] (33536 B)
    __shared__ __align__(16) char lds[64 * 262 * 2];
    char* base = lds;

    int b = blockIdx.x >> 6;
    int r = blockIdx.x & 63;
    int tid = threadIdx.x;

    // ---- stage A: S[b][c][r][0..63] -> At[p][c] bf16, XOR-swizzled ----
    // byte addr(p,c) = p*512 + (((c>>3) ^ (p&15)) << 4) + ((c&7)<<1)
    {
        int sub = tid & 3;
        int cl  = tid >> 2;                  // 0..63
        f32x4 v[16];
        #pragma unroll
        for (int chunk = 0; chunk < 4; ++chunk) {
            int c = chunk * 64 + cl;
            const float* src = S + (((size_t)(b * 256 + c) * 64 + r) * 64);
            #pragma unroll
            for (int k = 0; k < 4; ++k)
                v[chunk * 4 + k] = *reinterpret_cast<const f32x4*>(src + 16 * k + 4 * sub);
        }
        #pragma unroll
        for (int chunk = 0; chunk < 4; ++chunk) {
            int c = chunk * 64 + cl;
            #pragma unroll
            for (int k = 0; k < 4; ++k) {
                int p = 16 * k + 4 * sub;
                #pragma unroll
                for (int e = 0; e < 4; ++e) {
                    int pe = p + e;
                    int off = pe * 512 + ((((c >> 3) ^ (pe & 15))) << 4) + ((c & 7) << 1);
                    *reinterpret_cast<unsigned short*>(base + off) = f2bf(v[chunk * 4 + k][e]);
                }
            }
        }
    }
    __syncthreads();

    // ---- GEMM: wave w computes q in [64w, 64w+64), all 64 p rows, K=256 ----
    int w    = tid >> 6;
    int lane = tid & 63;
    int m    = lane & 15;
    int kg   = lane >> 4;

    const unsigned short* Db = Dt + ((size_t)(b * 256 + 64 * w)) * 256;

    f32x4 acc[4][4];
    #pragma unroll
    for (int i = 0; i < 4; ++i)
        #pragma unroll
        for (int j = 0; j < 4; ++j)
            acc[i][j] = f32x4{0.f, 0.f, 0.f, 0.f};

    #pragma unroll
    for (int step = 0; step < 8; ++step) {
        bf16x8 bfr[4];
        #pragma unroll
        for (int n = 0; n < 4; ++n)
            bfr[n] = *reinterpret_cast<const bf16x8*>(Db + (size_t)(16 * n + m) * 256 + step * 32 + kg * 8);
        bf16x8 af[4];
        #pragma unroll
        for (int pa = 0; pa < 4; ++pa) {
            int p = 16 * pa + m;
            int slot = (4 * step + kg) ^ m;          // p&15 == m
            af[pa] = *reinterpret_cast<const bf16x8*>(base + p * 512 + slot * 16);
        }
        #pragma unroll
        for (int pa = 0; pa < 4; ++pa)
            #pragma unroll
            for (int n = 0; n < 4; ++n)
                acc[pa][n] = __builtin_amdgcn_mfma_f32_16x16x32_bf16(af[pa], bfr[n], acc[pa][n], 0, 0, 0);
    }

    __syncthreads();   // all waves done reading At before overwrite

    // ---- dump G tile to LDS as bf16: gt[64 p][262] ----
    unsigned short* gt = (unsigned short*)base;
    #pragma unroll
    for (int pa = 0; pa < 4; ++pa)
        #pragma unroll
        for (int n = 0; n < 4; ++n)
            #pragma unroll
            for (int t = 0; t < 4; ++t) {
                int row = 16 * pa + 4 * kg + t;        // p local (spatial col)
                int col = 64 * w + 16 * n + m;         // q
                gt[row * 262 + col] = f2bf(acc[pa][n][t]);
            }
    __syncthreads();

    // ---- partials: P[b][r][i][x] = sum_j G[x+j][16i+j] (no atomics) ----
    int ilo = (r > 48) ? (r - 48) : 0;
    int ihi = (r < 15) ? r : 15;
    int total = (ihi - ilo + 1) * 49;
    for (int o = tid; o < total; o += 256) {
        int i = ilo + o / 49;
        int x = o % 49;
        float s = 0.f;
        int qb = 16 * i;
        #pragma unroll
        for (int j = 0; j < 16; ++j)
            s += bf2f(gt[(x + j) * 262 + qb + j]);
        P[((size_t)((b * 64 + r) * 16 + i)) * 52 + x] = s;
    }
}

// ---------- reduce partials: mm[b][y][x] = sum_i P[b][y+i][i][x] ----------
__global__ __launch_bounds__(256) void reduce_kernel(
    const float* __restrict__ P, float* __restrict__ mm) {
    int idx = blockIdx.x * 256 + threadIdx.x;
    if (idx >= 38416) return;
    int b  = idx / 2401;
    int yx = idx % 2401;
    int y  = yx / 49;
    int x  = yx % 49;
    float s = 0.f;
    #pragma unroll
    for (int i = 0; i < 16; ++i)
        s += P[((size_t)((b * 64 + y + i) * 16 + i)) * 52 + x];
    mm[idx] = s;
}

// ---------- fallback naive conv (tiny ws) ----------
__global__ __launch_bounds__(256) void conv_naive(
    const float* __restrict__ S, const float* __restrict__ D, float* __restrict__ mm) {
    int blk = blockIdx.x;            // b*2401 + y*49 + x
    int b = blk / 2401;
    int yx = blk % 2401;
    int y = yx / 49, x = yx % 49;
    int c = threadIdx.x;
    const float* Sp = S + (((size_t)b * 256 + c) * 64 + y) * 64 + x;
    const float* Dp = D + ((size_t)b * 256 + c) * 256;
    float s = 0.f;
    #pragma unroll
    for (int i = 0; i < 16; ++i)
        #pragma unroll 4
        for (int j = 0; j < 16; ++j)
            s += Sp[i * 64 + j] * Dp[i * 16 + j];
    __shared__ float red[256];
    red[c] = s;
    __syncthreads();
    for (int st = 128; st > 0; st >>= 1) {
        if (c < st) red[c] += red[c + st];
        __syncthreads();
    }
    if (c == 0) mm[blk] = red[0];
}

// ---------- global mean / rstd over 38416 values ----------
__global__ __launch_bounds__(1024) void stats_kernel(
    const float* __restrict__ mm, float* __restrict__ stats) {
    __shared__ float ssum[1024];
    __shared__ float ssq[1024];
    int tid = threadIdx.x;
    float s = 0.f, q = 0.f;
    for (int i = tid; i < 38416; i += 1024) {
        float v = mm[i];
        s += v; q += v * v;
    }
    ssum[tid] = s; ssq[tid] = q;
    __syncthreads();
    for (int st = 512; st > 0; st >>= 1) {
        if (tid < st) { ssum[tid] += ssum[tid + st]; ssq[tid] += ssq[tid + st]; }
        __syncthreads();
    }
    if (tid == 0) {
        float mean = ssum[0] / 38416.f;
        float var  = ssq[0] / 38416.f - mean * mean;
        stats[0] = mean;
        stats[1] = rsqrtf(var + 1e-5f);
    }
}

// ---------- normalize + bilinear 49x49 -> 256x256 ----------
__global__ __launch_bounds__(256) void bilinear_kernel(
    const float* __restrict__ mm, const float* __restrict__ stats,
    const float* __restrict__ gamma, const float* __restrict__ beta,
    float* __restrict__ out) {
    int idx = blockIdx.x * 256 + threadIdx.x;   // 16*256*256 = 1,048,576
    int b  = idx >> 16;
    int oy = (idx >> 8) & 255;
    int ox = idx & 255;
    const float scale = 49.0f / 256.0f;
    float cy = fminf(fmaxf((oy + 0.5f) * scale - 0.5f, 0.0f), 48.0f);
    int y0 = (int)cy; int y1 = min(y0 + 1, 48); float wy = cy - (float)y0;
    float cx = fminf(fmaxf((ox + 0.5f) * scale - 0.5f, 0.0f), 48.0f);
    int x0 = (int)cx; int x1 = min(x0 + 1, 48); float wx = cx - (float)x0;
    const float* mb = mm + (size_t)b * 2401;
    float v00 = mb[y0 * 49 + x0];
    float v01 = mb[y0 * 49 + x1];
    float v10 = mb[y1 * 49 + x0];
    float v11 = mb[y1 * 49 + x1];
    float r0 = v00 * (1.f - wy) + v10 * wy;
    float r1 = v01 * (1.f - wy) + v11 * wy;
    float v  = r0 * (1.f - wx) + r1 * wx;
    float mean = stats[0], rstd = stats[1];
    v = (v - mean) * rstd * gamma[0] + beta[0];
    out[idx] = v;
}

extern "C" void kernel_launch(void* const* d_in, const int* in_sizes, int n_in,
                              void* d_out, int out_size, void* d_ws, size_t ws_size,
                              hipStream_t stream) {
    const float* S     = (const float*)d_in[0];   // (16,256,64,64)
    const float* D     = (const float*)d_in[1];   // (16,256,16,16)
    const float* gamma = (const float*)d_in[2];   // (1,)
    const float* beta  = (const float*)d_in[3];   // (1,)
    float* out = (float*)d_out;                   // (16,1,256,256)

    char* ws = (char*)d_ws;
    const size_t sizeDt = (size_t)16 * 256 * 256 * 2;        // 2,097,152
    const size_t sizeMm = (size_t)38416 * 4;                 //   153,664
    const size_t sizeP  = (size_t)16 * 64 * 16 * 52 * 4;     // 3,407,872
    const size_t offDt = 0;
    const size_t offMm = offDt + sizeDt;
    const size_t offStats = offMm + sizeMm;
    const size_t offP = (offStats + 2 * sizeof(float) + 255) & ~(size_t)255;
    const size_t needFast = offP + sizeP;

    bool fast = (ws_size >= needFast);
    float* mm;
    float* stats;
    if (fast) {
        mm    = (float*)(ws + offMm);
        stats = (float*)(ws + offStats);
    } else {
        mm    = (float*)ws;
        stats = (float*)(ws + sizeMm);
    }

    if (fast) {
        unsigned short* Dt = (unsigned short*)(ws + offDt);
        float* P = (float*)(ws + offP);
        transposeD<<<dim3(8, 8, 16), dim3(32, 8), 0, stream>>>(D, Dt);
        conv_fused<<<1024, 256, 0, stream>>>(S, Dt, P);
        reduce_kernel<<<151, 256, 0, stream>>>(P, mm);
    } else {
        conv_naive<<<16 * 2401, 256, 0, stream>>>(S, D, mm);
    }
    stats_kernel<<<1, 1024, 0, stream>>>(mm, stats);
    bilinear_kernel<<<4096, 256, 0, stream>>>(mm, stats, gamma, beta, out);
}

// Round 4
// 43.139 us; speedup vs baseline: 2.0549x; 1.2081x over previous
//
#include <hip/hip_runtime.h>

// ---------- types ----------
using f32x4  = __attribute__((ext_vector_type(4))) float;
using bf16x8 = __attribute__((ext_vector_type(8))) short;   // 8 bf16 in 4 VGPRs

__device__ __forceinline__ unsigned short f2bf(float f) {
    union { float f; unsigned int u; } v; v.f = f;
    unsigned int r = v.u + 0x7fffu + ((v.u >> 16) & 1u);  // RNE
    return (unsigned short)(r >> 16);
}

__device__ __forceinline__ float bf2f(unsigned short u) {
    union { unsigned int u; float f; } v; v.u = ((unsigned int)u) << 16;
    return v.f;
}

// ---------- transpose D [16][256c][256q] f32 -> Dt [16][256q][256c] bf16; zero stats ----------
__global__ __launch_bounds__(256) void transposeD(
    const float* __restrict__ x, unsigned short* __restrict__ y, float* __restrict__ stats) {
    __shared__ float tile[32][33];
    int b  = blockIdx.z;
    int p0 = blockIdx.x * 32;      // q tile
    int c0 = blockIdx.y * 32;      // c tile
    const float* xb = x + (size_t)b * 256 * 256;
    unsigned short* yb = y + (size_t)b * 256 * 256;
    int tx = threadIdx.x, ty = threadIdx.y;
    #pragma unroll
    for (int i = 0; i < 32; i += 8)
        tile[ty + i][tx] = xb[(size_t)(c0 + ty + i) * 256 + (p0 + tx)];
    __syncthreads();
    int tid = ty * 32 + tx;
    #pragma unroll
    for (int k = 0; k < 2; ++k) {
        int wi = tid * 2 + k;          // 0..511
        int pl = wi >> 4;              // local q row
        int cp = wi & 15;              // c-pair
        unsigned short lo = f2bf(tile[2 * cp][pl]);
        unsigned short hi = f2bf(tile[2 * cp + 1][pl]);
        unsigned int packed = (unsigned int)lo | ((unsigned int)hi << 16);
        *reinterpret_cast<unsigned int*>(&yb[(size_t)(p0 + pl) * 256 + (c0 + 2 * cp)]) = packed;
    }
    if (blockIdx.x == 0 && blockIdx.y == 0 && blockIdx.z == 0 && tid == 0) {
        stats[0] = 0.f;
        stats[1] = 0.f;
    }
}

// ---------- fused conv: stage S->LDS(bf16,swizzled), GEMM vs Dt, partials to P ----------
// Block = (b, image row r). Computes G[p=r*64 .. r*64+64)[q=0..256) and writes
// 16-tap diagonal sums NON-ATOMICALLY to P[b][r][i][x].
//
// LDS A layout (bf16, XOR-swizzled for conflict-free ds_read_b128 / ds_write_b64):
//   byte(p, c) = p*512 + (((c>>3) ^ (p&15) ^ (p>>4)) << 4) + (c&7)*2
__global__ __launch_bounds__(256, 4) void conv_fused(
    const float* __restrict__ S,             // [16][256][64][64] f32
    const unsigned short* __restrict__ Dt,   // [16][256q][256c] bf16
    float* __restrict__ P) {                 // [16][64][16][52] f32 partials
    // union: At swizzled bf16 [64 p][256 c] (32768 B)  /  gt bf16 [64][262] (33536 B)
    __shared__ __align__(16) char lds[64 * 262 * 2];
    char* base = lds;

    int b = blockIdx.x >> 6;
    int r = blockIdx.x & 63;
    int tid = threadIdx.x;

    int w    = tid >> 6;          // wave 0..3
    int lane = tid & 63;
    int m    = lane & 15;
    int kg   = lane >> 4;
    const unsigned short* Db = Dt + ((size_t)(b * 256 + 64 * w)) * 256;

    // ---- stage: issue ALL 16 global loads, then convert+write ----
    // thread t: px = t&15 (p-group 4*px..4*px+3), cq = t>>4 (c-group 4*cq..4*cq+3 per round)
    int px = tid & 15;
    int cq = tid >> 4;
    const float* Sbr = S + ((size_t)b * 256 * 64 + r) * 64;   // + c*4096 + p

    f32x4 v[4][4];
    #pragma unroll
    for (int rho = 0; rho < 4; ++rho) {
        int c0 = rho * 64 + 4 * cq;
        #pragma unroll
        for (int j = 0; j < 4; ++j)
            v[rho][j] = *reinterpret_cast<const f32x4*>(Sbr + (size_t)(c0 + j) * 4096 + 4 * px);
    }
    // prefetch B for K-step 0 (stays in flight across the lgkm-only barrier)
    bf16x8 bcur[4];
    #pragma unroll
    for (int n = 0; n < 4; ++n)
        bcur[n] = *reinterpret_cast<const bf16x8*>(Db + (size_t)(16 * n + m) * 256 + kg * 8);
    __builtin_amdgcn_sched_barrier(0);   // keep all loads issued before any consumption

    // convert + in-register 4x4 transpose + ds_write_b64
    #pragma unroll
    for (int rho = 0; rho < 4; ++rho) {
        int slot = 8 * rho + (cq >> 1);
        int half = cq & 1;
        #pragma unroll
        for (int e = 0; e < 4; ++e) {
            int p = 4 * px + e;
            int swz = (p & 15) ^ (p >> 4);
            ushort4 o;
            o.x = f2bf(v[rho][0][e]);
            o.y = f2bf(v[rho][1][e]);
            o.z = f2bf(v[rho][2][e]);
            o.w = f2bf(v[rho][3][e]);
            *reinterpret_cast<ushort4*>(base + p * 512 + ((slot ^ swz) << 4) + half * 8) = o;
        }
    }
    // barrier that waits only for LDS writes; B-prefetch (vmcnt) stays in flight
    asm volatile("s_waitcnt lgkmcnt(0)" ::: "memory");
    __builtin_amdgcn_s_barrier();

    // ---- GEMM: wave w computes q in [64w, 64w+64), all 64 p rows, K=256 ----
    f32x4 acc[4][4];
    #pragma unroll
    for (int i = 0; i < 4; ++i)
        #pragma unroll
        for (int j = 0; j < 4; ++j)
            acc[i][j] = f32x4{0.f, 0.f, 0.f, 0.f};

    #pragma unroll
    for (int step = 0; step < 8; ++step) {
        bf16x8 bnext[4];
        if (step < 7) {
            #pragma unroll
            for (int n = 0; n < 4; ++n)
                bnext[n] = *reinterpret_cast<const bf16x8*>(
                    Db + (size_t)(16 * n + m) * 256 + (step + 1) * 32 + kg * 8);
        }
        bf16x8 af[4];
        #pragma unroll
        for (int pa = 0; pa < 4; ++pa) {
            int p = 16 * pa + m;
            int slot = (4 * step + kg) ^ m ^ pa;     // (c>>3) ^ (p&15) ^ (p>>4)
            af[pa] = *reinterpret_cast<const bf16x8*>(base + p * 512 + (slot << 4));
        }
        #pragma unroll
        for (int pa = 0; pa < 4; ++pa)
            #pragma unroll
            for (int n = 0; n < 4; ++n)
                acc[pa][n] = __builtin_amdgcn_mfma_f32_16x16x32_bf16(af[pa], bcur[n], acc[pa][n], 0, 0, 0);
        #pragma unroll
        for (int n = 0; n < 4; ++n)
            bcur[n] = bnext[n];
    }

    __syncthreads();   // all waves done reading At before overwrite

    // ---- dump G tile to LDS as bf16: gt[64 p][262] ----
    unsigned short* gt = (unsigned short*)base;
    #pragma unroll
    for (int pa = 0; pa < 4; ++pa)
        #pragma unroll
        for (int n = 0; n < 4; ++n)
            #pragma unroll
            for (int t = 0; t < 4; ++t) {
                int row = 16 * pa + 4 * kg + t;        // p local (spatial col)
                int col = 64 * w + 16 * n + m;         // q
                gt[row * 262 + col] = f2bf(acc[pa][n][t]);
            }
    __syncthreads();

    // ---- partials: P[b][r][i][x] = sum_j G[x+j][16i+j] (no atomics) ----
    int ilo = (r > 48) ? (r - 48) : 0;
    int ihi = (r < 15) ? r : 15;
    int total = (ihi - ilo + 1) * 49;
    for (int o = tid; o < total; o += 256) {
        int i = ilo + o / 49;
        int x = o % 49;
        float s = 0.f;
        int qb = 16 * i;
        #pragma unroll
        for (int j = 0; j < 16; ++j)
            s += bf2f(gt[(x + j) * 262 + qb + j]);
        P[((size_t)((b * 64 + r) * 16 + i)) * 52 + x] = s;
    }
}

// ---------- reduce partials + global stats: mm[b][y][x] = sum_i P[b][y+i][i][x] ----------
__global__ __launch_bounds__(256) void reduce_kernel(
    const float* __restrict__ P, float* __restrict__ mm, float* __restrict__ stats) {
    int idx = blockIdx.x * 256 + threadIdx.x;
    float s = 0.f;
    if (idx < 38416) {
        int b  = idx / 2401;
        int yx = idx % 2401;
        int y  = yx / 49;
        int x  = yx % 49;
        #pragma unroll
        for (int i = 0; i < 16; ++i)
            s += P[((size_t)((b * 64 + y + i) * 16 + i)) * 52 + x];
        mm[idx] = s;
    }
    // block-reduce (sum, sumsq), one atomic pair per block
    __shared__ float rs[256];
    __shared__ float rq[256];
    int tid = threadIdx.x;
    rs[tid] = (idx < 38416) ? s : 0.f;
    rq[tid] = (idx < 38416) ? s * s : 0.f;
    __syncthreads();
    for (int st = 128; st > 0; st >>= 1) {
        if (tid < st) { rs[tid] += rs[tid + st]; rq[tid] += rq[tid + st]; }
        __syncthreads();
    }
    if (tid == 0) {
        atomicAdd(&stats[0], rs[0]);
        atomicAdd(&stats[1], rq[0]);
    }
}

// ---------- fallback naive conv (tiny ws) ----------
__global__ __launch_bounds__(256) void conv_naive(
    const float* __restrict__ S, const float* __restrict__ D, float* __restrict__ mm) {
    int blk = blockIdx.x;            // b*2401 + y*49 + x
    int b = blk / 2401;
    int yx = blk % 2401;
    int y = yx / 49, x = yx % 49;
    int c = threadIdx.x;
    const float* Sp = S + (((size_t)b * 256 + c) * 64 + y) * 64 + x;
    const float* Dp = D + ((size_t)b * 256 + c) * 256;
    float s = 0.f;
    #pragma unroll
    for (int i = 0; i < 16; ++i)
        #pragma unroll 4
        for (int j = 0; j < 16; ++j)
            s += Sp[i * 64 + j] * Dp[i * 16 + j];
    __shared__ float red[256];
    red[c] = s;
    __syncthreads();
    for (int st = 128; st > 0; st >>= 1) {
        if (c < st) red[c] += red[c + st];
        __syncthreads();
    }
    if (c == 0) mm[blk] = red[0];
}

// ---------- fallback stats: raw sums over 38416 values ----------
__global__ __launch_bounds__(1024) void stats_kernel(
    const float* __restrict__ mm, float* __restrict__ stats) {
    __shared__ float ssum[1024];
    __shared__ float ssq[1024];
    int tid = threadIdx.x;
    float s = 0.f, q = 0.f;
    for (int i = tid; i < 38416; i += 1024) {
        float v = mm[i];
        s += v; q += v * v;
    }
    ssum[tid] = s; ssq[tid] = q;
    __syncthreads();
    for (int st = 512; st > 0; st >>= 1) {
        if (tid < st) { ssum[tid] += ssum[tid + st]; ssq[tid] += ssq[tid + st]; }
        __syncthreads();
    }
    if (tid == 0) {
        stats[0] = ssum[0];
        stats[1] = ssq[0];
    }
}

// ---------- normalize + bilinear 49x49 -> 256x256 (stats are raw sums) ----------
__global__ __launch_bounds__(256) void bilinear_kernel(
    const float* __restrict__ mm, const float* __restrict__ stats,
    const float* __restrict__ gamma, const float* __restrict__ beta,
    float* __restrict__ out) {
    int idx = blockIdx.x * 256 + threadIdx.x;   // 16*256*256 = 1,048,576
    int b  = idx >> 16;
    int oy = (idx >> 8) & 255;
    int ox = idx & 255;
    const float scale = 49.0f / 256.0f;
    float cy = fminf(fmaxf((oy + 0.5f) * scale - 0.5f, 0.0f), 48.0f);
    int y0 = (int)cy; int y1 = min(y0 + 1, 48); float wy = cy - (float)y0;
    float cx = fminf(fmaxf((ox + 0.5f) * scale - 0.5f, 0.0f), 48.0f);
    int x0 = (int)cx; int x1 = min(x0 + 1, 48); float wx = cx - (float)x0;
    const float* mb = mm + (size_t)b * 2401;
    float v00 = mb[y0 * 49 + x0];
    float v01 = mb[y0 * 49 + x1];
    float v10 = mb[y1 * 49 + x0];
    float v11 = mb[y1 * 49 + x1];
    float r0 = v00 * (1.f - wy) + v10 * wy;
    float r1 = v01 * (1.f - wy) + v11 * wy;
    float v  = r0 * (1.f - wx) + r1 * wx;
    const float invN = 1.0f / 38416.0f;
    float mean = stats[0] * invN;
    float var  = stats[1] * invN - mean * mean;
    float rstd = rsqrtf(var + 1e-5f);
    v = (v - mean) * rstd * gamma[0] + beta[0];
    out[idx] = v;
}

extern "C" void kernel_launch(void* const* d_in, const int* in_sizes, int n_in,
                              void* d_out, int out_size, void* d_ws, size_t ws_size,
                              hipStream_t stream) {
    const float* S     = (const float*)d_in[0];   // (16,256,64,64)
    const float* D     = (const float*)d_in[1];   // (16,256,16,16)
    const float* gamma = (const float*)d_in[2];   // (1,)
    const float* beta  = (const float*)d_in[3];   // (1,)
    float* out = (float*)d_out;                   // (16,1,256,256)

    char* ws = (char*)d_ws;
    const size_t sizeDt = (size_t)16 * 256 * 256 * 2;        // 2,097,152
    const size_t sizeMm = (size_t)38416 * 4;                 //   153,664
    const size_t sizeP  = (size_t)16 * 64 * 16 * 52 * 4;     // 3,407,872
    const size_t offDt = 0;
    const size_t offMm = offDt + sizeDt;
    const size_t offStats = offMm + sizeMm;
    const size_t offP = (offStats + 2 * sizeof(float) + 255) & ~(size_t)255;
    const size_t needFast = offP + sizeP;

    bool fast = (ws_size >= needFast);
    float* mm;
    float* stats;
    if (fast) {
        mm    = (float*)(ws + offMm);
        stats = (float*)(ws + offStats);
    } else {
        mm    = (float*)ws;
        stats = (float*)(ws + sizeMm);
    }

    if (fast) {
        unsigned short* Dt = (unsigned short*)(ws + offDt);
        float* P = (float*)(ws + offP);
        transposeD<<<dim3(8, 8, 16), dim3(32, 8), 0, stream>>>(D, Dt, stats);
        conv_fused<<<1024, 256, 0, stream>>>(S, Dt, P);
        reduce_kernel<<<151, 256, 0, stream>>>(P, mm, stats);
    } else {
        conv_naive<<<16 * 2401, 256, 0, stream>>>(S, D, mm);
        stats_kernel<<<1, 1024, 0, stream>>>(mm, stats);
    }
    bilinear_kernel<<<4096, 256, 0, stream>>>(mm, stats, gamma, beta, out);
}